// Round 6
// baseline (142.169 us; speedup 1.0000x reference)
//
#include <hip/hip_runtime.h>

#define L_SEQ 4096
#define DMODEL 256
#define DH 64
#define NKB 16   // key blocks (of 64) per workgroup: 4096 / 64 / ksplit(4)

typedef __attribute__((ext_vector_type(8))) __bf16 bf16x8;
typedef __attribute__((ext_vector_type(4))) float f32x4;
typedef __attribute__((ext_vector_type(16))) float f32x16;
typedef __attribute__((ext_vector_type(8))) unsigned short ushort8v;
typedef __attribute__((ext_vector_type(4))) unsigned short ushort4v;
typedef __attribute__((ext_vector_type(2))) unsigned int uint2v;
typedef __attribute__((ext_vector_type(4))) unsigned int uint4v;

__device__ __forceinline__ unsigned short f2bf(float f) {
  unsigned u = __builtin_bit_cast(unsigned, f);
  u += 0x7fffu + ((u >> 16) & 1u);
  return (unsigned short)(u >> 16);
}
__device__ __forceinline__ float bf2f(unsigned short h) {
  unsigned u = ((unsigned)h) << 16;
  return __builtin_bit_cast(float, u);
}
__device__ __forceinline__ bf16x8 ld_frag(const unsigned short* p) {
  return __builtin_bit_cast(bf16x8, *(const ushort8v*)p);
}
// pack 2 f32 -> 2 bf16 (RNE, same rounding as f2bf) in one VALU op
__device__ __forceinline__ unsigned cvtpk(float lo, float hi) {
  unsigned r;
  asm("v_cvt_pk_bf16_f32 %0, %1, %2" : "=v"(r) : "v"(lo), "v"(hi));
  return r;
}
// a.hi32lanes <-> b.lo32lanes (v_permlane32_swap_b32, gfx950)
__device__ __forceinline__ void plswap(unsigned& a, unsigned& b) {
  asm("v_permlane32_swap_b32 %0, %1" : "+v"(a), "+v"(b));
}
// raw v_exp_f32: D = 2^S0 (saves __expf's hidden *log2e mul; R4/R5-verified)
__device__ __forceinline__ float exp2raw(float x) {
  float r;
  asm("v_exp_f32 %0, %1" : "=v"(r) : "v"(x));
  return r;
}

// ---- 1. QKV GEMM, now reading q fp32 directly (k_transpose eliminated).
// A-tile: x[l][c] = q[b][c][l] staged via per-thread column reads (128B
// contiguous per lane) + scalar bf16 LDS writes (2-way bank alias = free).
// B-tile: w_qkv fp32 -> cvt_pk inline. Outputs Qh [p][l][d], QhT [p][d][l].
#define KP2 136
__global__ __launch_bounds__(256) void k_qkv(const float* __restrict__ q,
                                             const float* __restrict__ w,
                                             unsigned short* __restrict__ Qh,
                                             unsigned short* __restrict__ QhT) {
  __shared__ unsigned short As[64 * KP2];
  __shared__ unsigned short Bs[64 * KP2];
  int bx = blockIdx.x;
  int mtile = bx >> 2, h = bx & 3;
  int m0 = mtile * 64;
  int b = m0 >> 12, l0 = m0 & 4095;
  int t = threadIdx.x;
  int wv = t >> 6, lane = t & 63, g = lane >> 4, ln = lane & 15;
  int cA = t & 127, lh = t >> 7;   // A staging: c column, l half
  f32x4 acc[4] = {};
  for (int kb = 0; kb < 2; ++kb) {
    {  // A: As[l][cA] = bf16(q[b][kb*128+cA][l0+l]), l = lh*32 + 0..31
      const float* qp = q + ((size_t)(b * 256 + kb * 128 + cA)) * 4096 + l0 + lh * 32;
#pragma unroll
      for (int j4 = 0; j4 < 8; ++j4) {
        float4 v = *(const float4*)(qp + j4 * 4);
        int lrow = lh * 32 + j4 * 4;
        As[(lrow + 0) * KP2 + cA] = f2bf(v.x);
        As[(lrow + 1) * KP2 + cA] = f2bf(v.y);
        As[(lrow + 2) * KP2 + cA] = f2bf(v.z);
        As[(lrow + 3) * KP2 + cA] = f2bf(v.w);
      }
    }
#pragma unroll
    for (int it = 0; it < 4; ++it) {  // B: w fp32 -> bf16 inline
      int idx = t + it * 256;
      int row = idx >> 4;
      int c0 = (idx & 15) * 8;
      const float* wp = w + (size_t)(h * 64 + row) * 256 + kb * 128 + c0;
      float4 wa = *(const float4*)(wp);
      float4 wb = *(const float4*)(wp + 4);
      uint4v pk = {cvtpk(wa.x, wa.y), cvtpk(wa.z, wa.w), cvtpk(wb.x, wb.y), cvtpk(wb.z, wb.w)};
      *(uint4v*)(Bs + row * KP2 + c0) = pk;
    }
    __syncthreads();
#pragma unroll
    for (int kc = 0; kc < 4; ++kc) {
      bf16x8 a = ld_frag(As + (wv * 16 + ln) * KP2 + kc * 32 + g * 8);
#pragma unroll
      for (int tn = 0; tn < 4; ++tn) {
        bf16x8 bb = ld_frag(Bs + (tn * 16 + ln) * KP2 + kc * 32 + g * 8);
        acc[tn] = __builtin_amdgcn_mfma_f32_16x16x32_bf16(a, bb, acc[tn], 0, 0, 0);
      }
    }
    __syncthreads();
  }
  size_t pbase = (size_t)(b * 4 + h);
  // ---- epilogue: bounce tiles through LDS, then dense 16-B stores ----
#pragma unroll
  for (int tn = 0; tn < 4; ++tn) {
#pragma unroll
    for (int r = 0; r < 4; ++r) {
      int lrow = wv * 16 + g * 4 + r;
      int d = tn * 16 + ln;
      unsigned short bv = f2bf(acc[tn][r]);
      As[lrow * 64 + (((d >> 3) ^ (lrow & 7)) * 8) + (d & 7)] = bv;
      Bs[d * 64 + (((lrow >> 3) ^ (d & 7)) * 8) + (lrow & 7)] = bv;
    }
  }
#pragma unroll
  for (int s = 0; s < 2; ++s) {
    int flat = s * 64 + lane;
    int lrow = wv * 16 + (flat >> 3);
    int c8 = lane & 7;
    ushort8v v = *(const ushort8v*)(As + lrow * 64 + ((c8 ^ (lrow & 7)) * 8));
    *(ushort8v*)(Qh + (pbase * L_SEQ + l0 + lrow) * DH + c8 * 8) = v;
  }
  __syncthreads();
#pragma unroll
  for (int s = 0; s < 2; ++s) {
    int flat = s * 256 + t;
    int drow = flat >> 3;
    int c8 = t & 7;
    ushort8v v = *(const ushort8v*)(Bs + drow * 64 + ((c8 ^ (drow & 7)) * 8));
    *(ushort8v*)(QhT + (pbase * DH + drow) * L_SEQ + l0 + c8 * 8) = v;
  }
}

// ---- 2. flash attention, 8-wave wg: wave = (kw key-half, qh q-tile).
// R3/R5 diagnosis: latency-bound, no pipe >50%; every wave read the FULL
// K/V from LDS (4x duplication). kw-split halves per-wave LDS reads, MFMA
// count, and exp chain per barrier interval. kw-partials merged once at the
// end through the freed K/V LDS buffer ([chunk][lane] layout, conflict-free;
// lane<->(q,d) mapping identical across kw so merge is a pure add).
// Opart/Lpart stay KSN=4 (k_fc unchanged). grid 1024 = 8p x 32qsup x 4ks.
__global__ __launch_bounds__(512, 2) void k_attn(const unsigned short* __restrict__ Qh,
                                                 const unsigned short* __restrict__ QhT,
                                                 unsigned short* __restrict__ Opart,
                                                 float* __restrict__ Lpart) {
  constexpr float C1 = 0.18033688011112042f;   // 0.125 * log2(e)
  constexpr float C2 = -23.083120654223414f;   // -16 * log2(e)
  __shared__ unsigned short smem[4 * 4096];  // K0 V0 K1 V1; reused for O-merge
  __shared__ float lmerge[4][64];
  int bx = blockIdx.x;
  int p = bx & 7;
  int u = bx >> 3;
  int qsup = u & 31, ks = u >> 5;
  int t = threadIdx.x;
  int wv = t >> 6, lane = t & 63, ln = lane & 31, hi = lane >> 5;
  int kw = wv >> 2, qh = wv & 3;
  const unsigned short* Qp = Qh + (size_t)p * L_SEQ * DH;
  const unsigned short* QTp = QhT + (size_t)p * DH * L_SEQ;
  int q0 = qsup * 128;
  int qw = q0 + qh * 32;  // this wave's 32 q rows

  bf16x8 aQ[4];
#pragma unroll
  for (int kq = 0; kq < 4; ++kq)
    aQ[kq] = ld_frag(Qp + (size_t)(qw + ln) * DH + kq * 16 + hi * 8);

  f32x16 oacc[2] = {};   // [dt], O^T partial (this wave's key-half)
  float lacc = 0.f;

  // staging: 512 threads cover 64 rows x 8 chunks exactly once
  int srow = t >> 3, scol = t & 7;
  int sdst = srow * 64 + ((scol ^ (srow & 7)) * 8);

  ushort8v kreg, vreg;
  {
    int kbase = (ks * NKB) * 64;
    kreg = *(const ushort8v*)(Qp + (size_t)(kbase + srow) * DH + scol * 8);
    vreg = *(const ushort8v*)(QTp + (size_t)srow * L_SEQ + kbase + scol * 8);
  }

  for (int kb = 0; kb < NKB; ++kb) {
    unsigned short* Kc = smem + (kb & 1) * 8192;
    unsigned short* Vc = Kc + 4096;
    *(ushort8v*)(Kc + sdst) = kreg;
    *(ushort8v*)(Vc + sdst) = vreg;
    __syncthreads();
    if (kb + 1 < NKB) {
      int kbase = (ks * NKB + kb + 1) * 64;
      kreg = *(const ushort8v*)(Qp + (size_t)(kbase + srow) * DH + scol * 8);
      vreg = *(const ushort8v*)(QTp + (size_t)srow * L_SEQ + kbase + scol * 8);
    }
    // ---- this wave's 32 keys only (kw half) ----
    int key = kw * 32 + ln;
    bf16x8 aK[4];
#pragma unroll
    for (int kq = 0; kq < 4; ++kq)
      aK[kq] = ld_frag(Kc + key * 64 + (((kq * 2 + hi) ^ (key & 7)) * 8));
    f32x16 s = {};
#pragma unroll
    for (int kq = 0; kq < 4; ++kq)
      s = __builtin_amdgcn_mfma_f32_32x32x16_bf16(aK[kq], aQ[kq], s, 0, 0, 0);
    // fixed-max softmax: p = 2^(s*C1 + C2) == exp(s/8 - 16)
    float pv[16];
#pragma unroll
    for (int r = 0; r < 16; ++r) pv[r] = exp2raw(fmaf(s[r], C1, C2));
    lacc += (((pv[0] + pv[1]) + (pv[2] + pv[3])) + ((pv[4] + pv[5]) + (pv[6] + pv[7]))) +
            (((pv[8] + pv[9]) + (pv[10] + pv[11])) + ((pv[12] + pv[13]) + (pv[14] + pv[15])));
    unsigned w0 = cvtpk(pv[0], pv[1]), w1 = cvtpk(pv[2], pv[3]);
    unsigned w2 = cvtpk(pv[4], pv[5]), w3 = cvtpk(pv[6], pv[7]);
    unsigned w4 = cvtpk(pv[8], pv[9]), w5 = cvtpk(pv[10], pv[11]);
    unsigned w6 = cvtpk(pv[12], pv[13]), w7 = cvtpk(pv[14], pv[15]);
    plswap(w0, w2);
    plswap(w1, w3);
    plswap(w4, w6);
    plswap(w5, w7);
    uint4v c0 = {w0, w1, w2, w3};
    uint4v c1 = {w4, w5, w6, w7};
    bf16x8 pf0 = __builtin_bit_cast(bf16x8, c0);
    bf16x8 pf1 = __builtin_bit_cast(bf16x8, c1);
#pragma unroll
    for (int dt = 0; dt < 2; ++dt) {
      int d = dt * 32 + ln;
      bf16x8 vf0 = ld_frag(Vc + d * 64 + (((kw * 4 + 0 + hi) ^ (d & 7)) * 8));
      bf16x8 vf1 = ld_frag(Vc + d * 64 + (((kw * 4 + 2 + hi) ^ (d & 7)) * 8));
      oacc[dt] = __builtin_amdgcn_mfma_f32_32x32x16_bf16(vf0, pf0, oacc[dt], 0, 0, 0);
      oacc[dt] = __builtin_amdgcn_mfma_f32_32x32x16_bf16(vf1, pf1, oacc[dt], 0, 0, 0);
    }
  }
  // ---- kw merge: kw=1 -> LDS (conflict-free [chunk][lane]), kw=0 adds ----
  __syncthreads();   // all waves done reading Kc/Vc; smem is free
  float* smf = (float*)smem;
  if (kw == 1) {
#pragma unroll
    for (int dt = 0; dt < 2; ++dt)
#pragma unroll
      for (int g4 = 0; g4 < 4; ++g4) {
        f32x4 c4 = {oacc[dt][g4 * 4 + 0], oacc[dt][g4 * 4 + 1],
                    oacc[dt][g4 * 4 + 2], oacc[dt][g4 * 4 + 3]};
        *(f32x4*)(smf + qh * 2048 + (dt * 4 + g4) * 256 + lane * 4) = c4;
      }
    lmerge[qh][lane] = lacc;
  }
  __syncthreads();
  if (kw == 0) {
#pragma unroll
    for (int dt = 0; dt < 2; ++dt)
#pragma unroll
      for (int g4 = 0; g4 < 4; ++g4) {
        f32x4 c4 = *(const f32x4*)(smf + qh * 2048 + (dt * 4 + g4) * 256 + lane * 4);
#pragma unroll
        for (int j = 0; j < 4; ++j) oacc[dt][g4 * 4 + j] += c4[j];
      }
    lacc += lmerge[qh][lane];
    lacc += __shfl_xor(lacc, 32, 64);
    size_t pq = (size_t)(ks * 8 + p) * L_SEQ;
    if (lane < 32) Lpart[pq + qw + ln] = lacc;
    // O^T epilogue (R5-verified pattern): lane owns q = qw+ln;
    // reg r -> d = dt*32 + (r>>2)*8 + hi*4 + (r&3); cvt_pk pairs -> 8B stores.
#pragma unroll
    for (int dt = 0; dt < 2; ++dt) {
      size_t rb = (pq + qw + ln) * DH + dt * 32 + hi * 4;
#pragma unroll
      for (int g8 = 0; g8 < 4; ++g8) {
        uint2v wv2 = {cvtpk(oacc[dt][g8 * 4 + 0], oacc[dt][g8 * 4 + 1]),
                      cvtpk(oacc[dt][g8 * 4 + 2], oacc[dt][g8 * 4 + 3])};
        *(uint2v*)(Opart + rb + g8 * 8) = wv2;
      }
    }
  }
}

// ---- 3. FC GEMM + bias + residual + LayerNorm (R5 structure, passed).
// Only change: Bs staged from fc_w fp32 with inline cvt (fcwbf eliminated).
#define CP 72
__global__ __launch_bounds__(256) void k_fc(const unsigned short* __restrict__ Opart,
                                            const float* __restrict__ Lpart,
                                            const float* __restrict__ fcw,
                                            const float* __restrict__ qres,
                                            const float* __restrict__ fcb,
                                            const float* __restrict__ lng,
                                            const float* __restrict__ lnb,
                                            float* __restrict__ out) {
  __shared__ unsigned short As[16 * CP];
  __shared__ unsigned short Bs[256 * CP];
  __shared__ float resT[256 * 17];   // [c][l], +1 pad
  __shared__ float outB[16 * 260];   // [l][c], pad to 260 for aligned b128
  __shared__ float redS[4][16], redQ[4][16], muA[16], rsA[16];
  int bx = blockIdx.x;
  int m0 = bx * 16;
  int b = m0 >> 12, lpart = m0 & 4095;
  int t = threadIdx.x;
  int wv = t >> 6, lane = t & 63, g = lane >> 4, ln = lane & 15;

  // residual tile: qres[b, c, lpart..lpart+15] -> resT[c][l] (coalesced 64B/row)
#pragma unroll
  for (int it = 0; it < 4; ++it) {
    int c = (t >> 2) + it * 64;
    int l4 = (t & 3) * 4;
    float4 v = *(const float4*)(qres + ((size_t)(b * 256 + c)) * 4096 + lpart + l4);
    resT[c * 17 + l4 + 0] = v.x;
    resT[c * 17 + l4 + 1] = v.y;
    resT[c * 17 + l4 + 2] = v.z;
    resT[c * 17 + l4 + 3] = v.w;
  }

  f32x4 acc[4] = {};
  for (int kb = 0; kb < 4; ++kb) {   // kb == head index for A-staging
    if (t < 128) {
      int row = t >> 3, c0 = (t & 7) * 8;
      int q = lpart + row;
      int p = b * 4 + kb;
      float lsum = Lpart[(size_t)(0 * 8 + p) * L_SEQ + q] +
                   Lpart[(size_t)(1 * 8 + p) * L_SEQ + q] +
                   Lpart[(size_t)(2 * 8 + p) * L_SEQ + q] +
                   Lpart[(size_t)(3 * 8 + p) * L_SEQ + q];
      float inv = 1.0f / lsum;
      float a8[8] = {0.f, 0.f, 0.f, 0.f, 0.f, 0.f, 0.f, 0.f};
#pragma unroll
      for (int ksp = 0; ksp < 4; ++ksp) {
        ushort8v v = *(const ushort8v*)(Opart + ((size_t)(ksp * 8 + p) * L_SEQ + q) * DH + c0);
#pragma unroll
        for (int j = 0; j < 8; ++j) a8[j] += bf2f(v[j]);
      }
      ushort8v o;
#pragma unroll
      for (int j = 0; j < 8; ++j) o[j] = f2bf(a8[j] * inv);
      *(ushort8v*)(As + row * CP + c0) = o;
    }
#pragma unroll
    for (int it = 0; it < 8; ++it) {
      int idx = t + it * 256;
      int row = idx >> 3, c0 = (idx & 7) * 8;
      const float* wp = fcw + (size_t)row * 256 + kb * 64 + c0;
      float4 wa = *(const float4*)(wp);
      float4 wb = *(const float4*)(wp + 4);
      uint4v pk = {cvtpk(wa.x, wa.y), cvtpk(wa.z, wa.w), cvtpk(wb.x, wb.y), cvtpk(wb.z, wb.w)};
      *(uint4v*)(Bs + row * CP + c0) = pk;
    }
    __syncthreads();
#pragma unroll
    for (int kc = 0; kc < 2; ++kc) {
      bf16x8 a = ld_frag(As + ln * CP + kc * 32 + g * 8);
      bf16x8 bb[4];
#pragma unroll
      for (int tn = 0; tn < 4; ++tn) bb[tn] = ld_frag(Bs + (wv * 64 + tn * 16 + ln) * CP + kc * 32 + g * 8);
#pragma unroll
      for (int tn = 0; tn < 4; ++tn)
        acc[tn] = __builtin_amdgcn_mfma_f32_16x16x32_bf16(a, bb[tn], acc[tn], 0, 0, 0);
    }
    __syncthreads();
  }
  float fb[4], lg[4], lb[4];
#pragma unroll
  for (int tn = 0; tn < 4; ++tn) {
    int o = wv * 64 + tn * 16 + ln;
    fb[tn] = fcb[o]; lg[tn] = lng[o]; lb[tn] = lnb[o];
  }
  {
    float ps[4] = {0.f, 0.f, 0.f, 0.f}, pq2[4] = {0.f, 0.f, 0.f, 0.f};
#pragma unroll
    for (int tn = 0; tn < 4; ++tn) {
      int o = wv * 64 + tn * 16 + ln;
#pragma unroll
      for (int r = 0; r < 4; ++r) {
        float v = acc[tn][r] + fb[tn] + resT[o * 17 + g * 4 + r];
        acc[tn][r] = v;
        ps[r] += v;
        pq2[r] += v * v;
      }
    }
#pragma unroll
    for (int r = 0; r < 4; ++r) {
      float s = ps[r], q2 = pq2[r];
#pragma unroll
      for (int off = 1; off < 16; off <<= 1) {
        s += __shfl_xor(s, off, 64);
        q2 += __shfl_xor(q2, off, 64);
      }
      if (ln == 0) {
        int row = g * 4 + r;
        redS[wv][row] = s;
        redQ[wv][row] = q2;
      }
    }
  }
  __syncthreads();
  if (t < 16) {
    float s = redS[0][t] + redS[1][t] + redS[2][t] + redS[3][t];
    float q2 = redQ[0][t] + redQ[1][t] + redQ[2][t] + redQ[3][t];
    float mu = s * (1.f / 256.f);
    float var = q2 * (1.f / 256.f) - mu * mu;
    muA[t] = mu;
    rsA[t] = rsqrtf(var + 1e-5f);
  }
  __syncthreads();
  // normalize into outB [l][c], then coalesced full-row stores
#pragma unroll
  for (int r = 0; r < 4; ++r) {
    int row = g * 4 + r;
    float mu = muA[row], rs = rsA[row];
#pragma unroll
    for (int tn = 0; tn < 4; ++tn) {
      int o = wv * 64 + tn * 16 + ln;
      outB[row * 260 + o] = (acc[tn][r] - mu) * rs * lg[tn] + lb[tn];
    }
  }
  __syncthreads();
#pragma unroll
  for (int it = 0; it < 4; ++it) {
    int idx = it * 256 + t;
    int row = idx >> 6;
    int c4 = (idx & 63) * 4;
    float4 v = *(const float4*)(outB + row * 260 + c4);
    *(float4*)(out + (size_t)(m0 + row) * 256 + c4) = v;
  }
}

extern "C" void kernel_launch(void* const* d_in, const int* in_sizes, int n_in,
                              void* d_out, int out_size, void* d_ws, size_t ws_size,
                              hipStream_t stream) {
  const float* q = (const float*)d_in[0];
  const float* w_qkv = (const float*)d_in[1];
  const float* fc_w = (const float*)d_in[2];
  const float* fc_b = (const float*)d_in[3];
  const float* ln_g = (const float*)d_in[4];
  const float* ln_b = (const float*)d_in[5];
  float* out = (float*)d_out;

  // workspace (shorts): Qh 4MB | QhT 4MB | Opart 16.7MB | Lpart 0.5MB  (~25.7MB)
  unsigned short* Qh = (unsigned short*)d_ws;    // [p][l][d]
  unsigned short* QhT = Qh + 2097152;            // [p][d][l]
  unsigned short* Opart = QhT + 2097152;         // [ks][p][q][d] bf16, 4*2M
  float* Lpart = (float*)(Opart + 8388608);      // [ks][p][q] fp32

  k_qkv<<<dim3(512), dim3(256), 0, stream>>>(q, w_qkv, Qh, QhT);
  k_attn<<<dim3(1024), dim3(512), 0, stream>>>(Qh, QhT, Opart, Lpart);
  k_fc<<<dim3(512), dim3(256), 0, stream>>>(Opart, Lpart, fc_w, q, fc_b, ln_g, ln_b, out);
}

// Round 7
// 136.973 us; speedup vs baseline: 1.0379x; 1.0379x over previous
//
#include <hip/hip_runtime.h>

#define L_SEQ 4096
#define DMODEL 256
#define DH 64
#define NKB 16   // key blocks (of 64) per workgroup: 4096 / 64 / ksplit(4)

typedef __attribute__((ext_vector_type(8))) __bf16 bf16x8;
typedef __attribute__((ext_vector_type(4))) float f32x4;
typedef __attribute__((ext_vector_type(16))) float f32x16;
typedef __attribute__((ext_vector_type(8))) unsigned short ushort8v;
typedef __attribute__((ext_vector_type(4))) unsigned short ushort4v;
typedef __attribute__((ext_vector_type(2))) unsigned int uint2v;
typedef __attribute__((ext_vector_type(4))) unsigned int uint4v;

__device__ __forceinline__ unsigned short f2bf(float f) {
  unsigned u = __builtin_bit_cast(unsigned, f);
  u += 0x7fffu + ((u >> 16) & 1u);
  return (unsigned short)(u >> 16);
}
__device__ __forceinline__ float bf2f(unsigned short h) {
  unsigned u = ((unsigned)h) << 16;
  return __builtin_bit_cast(float, u);
}
__device__ __forceinline__ bf16x8 ld_frag(const unsigned short* p) {
  return __builtin_bit_cast(bf16x8, *(const ushort8v*)p);
}
// pack 2 f32 -> 2 bf16 (RNE, same rounding as f2bf) in one VALU op
__device__ __forceinline__ unsigned cvtpk(float lo, float hi) {
  unsigned r;
  asm("v_cvt_pk_bf16_f32 %0, %1, %2" : "=v"(r) : "v"(lo), "v"(hi));
  return r;
}
// a.hi32lanes <-> b.lo32lanes (v_permlane32_swap_b32, gfx950)
__device__ __forceinline__ void plswap(unsigned& a, unsigned& b) {
  asm("v_permlane32_swap_b32 %0, %1" : "+v"(a), "+v"(b));
}
// raw v_exp_f32: D = 2^S0 (saves __expf's hidden *log2e mul; R4/R5-verified)
__device__ __forceinline__ float exp2raw(float x) {
  float r;
  asm("v_exp_f32 %0, %1" : "=v"(r) : "v"(x));
  return r;
}

// ---- 1. QKV GEMM with fused transpose (k_transpose eliminated PROPERLY).
// R6's fusion regressed because A-staging used 32 scalar ds_write_u16/thread.
// This version replicates R5's verified k_transpose pattern INSIDE the kernel:
// per kb, stage q fp32 into T[128][65] (float4 reads, scalar f32 LDS writes,
// 2-way bank alias = free), then build As[64][KP2] bf16 via vectorized
// f2bf -> ushort8 writes (bit-identical values to the R5 two-kernel path).
// B-tile: w_qkv fp32 -> cvtpk inline (R6-verified). 3 barriers per kb.
#define KP2 136
__global__ __launch_bounds__(256) void k_qkv(const float* __restrict__ q,
                                             const float* __restrict__ w,
                                             unsigned short* __restrict__ Qh,
                                             unsigned short* __restrict__ QhT) {
  __shared__ float T[128 * 65];              // 33.3 KB fp32 transpose tile
  __shared__ unsigned short As[64 * KP2];    // 17.4 KB
  __shared__ unsigned short Bs[64 * KP2];    // 17.4 KB  (total ~68 KB, 2 wg/CU)
  int bx = blockIdx.x;
  int mtile = bx >> 2, h = bx & 3;
  int m0 = mtile * 64;
  int b = m0 >> 12, l0 = m0 & 4095;
  int t = threadIdx.x;
  int wv = t >> 6, lane = t & 63, g = lane >> 4, ln = lane & 15;
  f32x4 acc[4] = {};
  for (int kb = 0; kb < 2; ++kb) {
    // T[c][l] <- q[b][kb*128+c][l0+l], c=0..127, l=0..63 (float4 rows)
#pragma unroll
    for (int it = 0; it < 8; ++it) {
      int i = (t >> 4) + it * 16;          // c within this kb's 128 channels
      int j0 = (t & 15) * 4;               // l
      float4 v = *(const float4*)(q + ((size_t)(b * 256 + kb * 128 + i)) * 4096 + l0 + j0);
      T[i * 65 + j0 + 0] = v.x;
      T[i * 65 + j0 + 1] = v.y;
      T[i * 65 + j0 + 2] = v.z;
      T[i * 65 + j0 + 3] = v.w;
    }
    // Bs: w fp32 -> bf16 inline (R6-verified pattern)
#pragma unroll
    for (int it = 0; it < 4; ++it) {
      int idx = t + it * 256;
      int row = idx >> 4;
      int c0 = (idx & 15) * 8;
      const float* wp = w + (size_t)(h * 64 + row) * 256 + kb * 128 + c0;
      float4 wa = *(const float4*)(wp);
      float4 wb = *(const float4*)(wp + 4);
      uint4v pk = {cvtpk(wa.x, wa.y), cvtpk(wa.z, wa.w), cvtpk(wb.x, wb.y), cvtpk(wb.z, wb.w)};
      *(uint4v*)(Bs + row * KP2 + c0) = pk;
    }
    __syncthreads();   // T, Bs visible
    // As[l][c] <- bf16(T[c][l]): vectorized 8-channel gather per thread
#pragma unroll
    for (int it = 0; it < 4; ++it) {
      int idx = t + it * 256;
      int row = idx >> 4;                  // l
      int c0 = (idx & 15) * 8;             // c chunk
      ushort8v o;
#pragma unroll
      for (int k = 0; k < 8; ++k) o[k] = f2bf(T[(c0 + k) * 65 + row]);
      *(ushort8v*)(As + row * KP2 + c0) = o;
    }
    __syncthreads();   // As visible
#pragma unroll
    for (int kc = 0; kc < 4; ++kc) {
      bf16x8 a = ld_frag(As + (wv * 16 + ln) * KP2 + kc * 32 + g * 8);
#pragma unroll
      for (int tn = 0; tn < 4; ++tn) {
        bf16x8 bb = ld_frag(Bs + (tn * 16 + ln) * KP2 + kc * 32 + g * 8);
        acc[tn] = __builtin_amdgcn_mfma_f32_16x16x32_bf16(a, bb, acc[tn], 0, 0, 0);
      }
    }
    __syncthreads();   // done reading As/Bs/T before next kb overwrites
  }
  size_t pbase = (size_t)(b * 4 + h);
  // ---- epilogue: bounce tiles through LDS, then dense 16-B stores ----
#pragma unroll
  for (int tn = 0; tn < 4; ++tn) {
#pragma unroll
    for (int r = 0; r < 4; ++r) {
      int lrow = wv * 16 + g * 4 + r;
      int d = tn * 16 + ln;
      unsigned short bv = f2bf(acc[tn][r]);
      As[lrow * 64 + (((d >> 3) ^ (lrow & 7)) * 8) + (d & 7)] = bv;
      Bs[d * 64 + (((lrow >> 3) ^ (d & 7)) * 8) + (lrow & 7)] = bv;
    }
  }
#pragma unroll
  for (int s = 0; s < 2; ++s) {
    int flat = s * 64 + lane;
    int lrow = wv * 16 + (flat >> 3);
    int c8 = lane & 7;
    ushort8v v = *(const ushort8v*)(As + lrow * 64 + ((c8 ^ (lrow & 7)) * 8));
    *(ushort8v*)(Qh + (pbase * L_SEQ + l0 + lrow) * DH + c8 * 8) = v;
  }
  __syncthreads();
#pragma unroll
  for (int s = 0; s < 2; ++s) {
    int flat = s * 256 + t;
    int drow = flat >> 3;
    int c8 = t & 7;
    ushort8v v = *(const ushort8v*)(Bs + drow * 64 + ((c8 ^ (drow & 7)) * 8));
    *(ushort8v*)(QhT + (pbase * DH + drow) * L_SEQ + l0 + c8 * 8) = v;
  }
}

// ---- 2. flash attention: R5's exact verified body (53.5us, best of R1/R3/R5/R6
// variants; R6 proved further occupancy/split restructuring is a null here).
// grid 1024 = 8p x 32qsup x 4ks.
__global__ __launch_bounds__(256, 2) void k_attn(const unsigned short* __restrict__ Qh,
                                                 const unsigned short* __restrict__ QhT,
                                                 unsigned short* __restrict__ Opart,
                                                 float* __restrict__ Lpart) {
  constexpr float C1 = 0.18033688011112042f;   // 0.125 * log2(e)
  constexpr float C2 = -23.083120654223414f;   // -16 * log2(e)
  __shared__ unsigned short smem[4 * 4096];  // K0 V0 K1 V1, 8KB each, 32 KB
  int bx = blockIdx.x;
  int p = bx & 7;
  int u = bx >> 3;
  int qsup = u & 31, ks = u >> 5;
  int t = threadIdx.x;
  int wv = t >> 6, lane = t & 63, ln = lane & 31, hi = lane >> 5;
  const unsigned short* Qp = Qh + (size_t)p * L_SEQ * DH;
  const unsigned short* QTp = QhT + (size_t)p * DH * L_SEQ;
  int q0 = qsup * 128;
  int qw = q0 + wv * 32;  // this wave's 32 q rows

  bf16x8 aQ[4];
#pragma unroll
  for (int kq = 0; kq < 4; ++kq)
    aQ[kq] = ld_frag(Qp + (size_t)(qw + ln) * DH + kq * 16 + hi * 8);

  f32x16 oacc[2] = {};   // [dt], O^T fragments
  float lacc = 0.f;      // per-lane partial l (half the keys)

  int srow0 = t >> 3, scol = t & 7;
  int srow1 = srow0 + 32;
  int sdst0 = srow0 * 64 + ((scol ^ (srow0 & 7)) * 8);
  int sdst1 = srow1 * 64 + ((scol ^ (srow1 & 7)) * 8);

  ushort8v kreg0, kreg1, vreg0, vreg1;
  {
    int kbase = (ks * NKB) * 64;
    kreg0 = *(const ushort8v*)(Qp + (size_t)(kbase + srow0) * DH + scol * 8);
    kreg1 = *(const ushort8v*)(Qp + (size_t)(kbase + srow1) * DH + scol * 8);
    vreg0 = *(const ushort8v*)(QTp + (size_t)srow0 * L_SEQ + kbase + scol * 8);
    vreg1 = *(const ushort8v*)(QTp + (size_t)srow1 * L_SEQ + kbase + scol * 8);
  }

  for (int kb = 0; kb < NKB; ++kb) {
    unsigned short* Kc = smem + (kb & 1) * 8192;
    unsigned short* Vc = Kc + 4096;
    *(ushort8v*)(Kc + sdst0) = kreg0;
    *(ushort8v*)(Kc + sdst1) = kreg1;
    *(ushort8v*)(Vc + sdst0) = vreg0;
    *(ushort8v*)(Vc + sdst1) = vreg1;
    __syncthreads();
    if (kb + 1 < NKB) {
      int kbase = (ks * NKB + kb + 1) * 64;
      kreg0 = *(const ushort8v*)(Qp + (size_t)(kbase + srow0) * DH + scol * 8);
      kreg1 = *(const ushort8v*)(Qp + (size_t)(kbase + srow1) * DH + scol * 8);
      vreg0 = *(const ushort8v*)(QTp + (size_t)srow0 * L_SEQ + kbase + scol * 8);
      vreg1 = *(const ushort8v*)(QTp + (size_t)srow1 * L_SEQ + kbase + scol * 8);
    }
#pragma unroll
    for (int mt = 0; mt < 2; ++mt) {
      int key = mt * 32 + ln;
      bf16x8 aK[4];
#pragma unroll
      for (int kq = 0; kq < 4; ++kq)
        aK[kq] = ld_frag(Kc + key * 64 + (((kq * 2 + hi) ^ (key & 7)) * 8));
      f32x16 s = {};
#pragma unroll
      for (int kq = 0; kq < 4; ++kq)
        s = __builtin_amdgcn_mfma_f32_32x32x16_bf16(aK[kq], aQ[kq], s, 0, 0, 0);
      // fixed-max softmax: p = 2^(s*C1 + C2) == exp(s/8 - 16)
      float pv[16];
#pragma unroll
      for (int r = 0; r < 16; ++r) pv[r] = exp2raw(fmaf(s[r], C1, C2));
      lacc += (((pv[0] + pv[1]) + (pv[2] + pv[3])) + ((pv[4] + pv[5]) + (pv[6] + pv[7]))) +
              (((pv[8] + pv[9]) + (pv[10] + pv[11])) + ((pv[12] + pv[13]) + (pv[14] + pv[15])));
      unsigned w0 = cvtpk(pv[0], pv[1]), w1 = cvtpk(pv[2], pv[3]);
      unsigned w2 = cvtpk(pv[4], pv[5]), w3 = cvtpk(pv[6], pv[7]);
      unsigned w4 = cvtpk(pv[8], pv[9]), w5 = cvtpk(pv[10], pv[11]);
      unsigned w6 = cvtpk(pv[12], pv[13]), w7 = cvtpk(pv[14], pv[15]);
      plswap(w0, w2);
      plswap(w1, w3);
      plswap(w4, w6);
      plswap(w5, w7);
      uint4v c0 = {w0, w1, w2, w3};
      uint4v c1 = {w4, w5, w6, w7};
      bf16x8 pf0 = __builtin_bit_cast(bf16x8, c0);
      bf16x8 pf1 = __builtin_bit_cast(bf16x8, c1);
#pragma unroll
      for (int dt = 0; dt < 2; ++dt) {
        int d = dt * 32 + ln;
        bf16x8 vf0 = ld_frag(Vc + d * 64 + (((mt * 4 + 0 * 2 + hi) ^ (d & 7)) * 8));
        bf16x8 vf1 = ld_frag(Vc + d * 64 + (((mt * 4 + 1 * 2 + hi) ^ (d & 7)) * 8));
        oacc[dt] = __builtin_amdgcn_mfma_f32_32x32x16_bf16(vf0, pf0, oacc[dt], 0, 0, 0);
        oacc[dt] = __builtin_amdgcn_mfma_f32_32x32x16_bf16(vf1, pf1, oacc[dt], 0, 0, 0);
      }
    }
  }
  lacc += __shfl_xor(lacc, 32, 64);
  size_t pq = (size_t)(ks * 8 + p) * L_SEQ;
  if (lane < 32) Lpart[pq + qw + ln] = lacc;
#pragma unroll
  for (int dt = 0; dt < 2; ++dt) {
    size_t rb = (pq + qw + ln) * DH + dt * 32 + hi * 4;
#pragma unroll
    for (int g8 = 0; g8 < 4; ++g8) {
      uint2v wv2 = {cvtpk(oacc[dt][g8 * 4 + 0], oacc[dt][g8 * 4 + 1]),
                    cvtpk(oacc[dt][g8 * 4 + 2], oacc[dt][g8 * 4 + 3])};
      *(uint2v*)(Opart + rb + g8 * 8) = wv2;
    }
  }
}

// ---- 3. FC GEMM + bias + residual + LayerNorm (R6's exact verified body:
// R5 structure + inline fc_w conversion).
#define CP 72
__global__ __launch_bounds__(256) void k_fc(const unsigned short* __restrict__ Opart,
                                            const float* __restrict__ Lpart,
                                            const float* __restrict__ fcw,
                                            const float* __restrict__ qres,
                                            const float* __restrict__ fcb,
                                            const float* __restrict__ lng,
                                            const float* __restrict__ lnb,
                                            float* __restrict__ out) {
  __shared__ unsigned short As[16 * CP];
  __shared__ unsigned short Bs[256 * CP];
  __shared__ float resT[256 * 17];   // [c][l], +1 pad
  __shared__ float outB[16 * 260];   // [l][c], pad to 260 for aligned b128
  __shared__ float redS[4][16], redQ[4][16], muA[16], rsA[16];
  int bx = blockIdx.x;
  int m0 = bx * 16;
  int b = m0 >> 12, lpart = m0 & 4095;
  int t = threadIdx.x;
  int wv = t >> 6, lane = t & 63, g = lane >> 4, ln = lane & 15;

  // residual tile: qres[b, c, lpart..lpart+15] -> resT[c][l] (coalesced 64B/row)
#pragma unroll
  for (int it = 0; it < 4; ++it) {
    int c = (t >> 2) + it * 64;
    int l4 = (t & 3) * 4;
    float4 v = *(const float4*)(qres + ((size_t)(b * 256 + c)) * 4096 + lpart + l4);
    resT[c * 17 + l4 + 0] = v.x;
    resT[c * 17 + l4 + 1] = v.y;
    resT[c * 17 + l4 + 2] = v.z;
    resT[c * 17 + l4 + 3] = v.w;
  }

  f32x4 acc[4] = {};
  for (int kb = 0; kb < 4; ++kb) {   // kb == head index for A-staging
    if (t < 128) {
      int row = t >> 3, c0 = (t & 7) * 8;
      int q = lpart + row;
      int p = b * 4 + kb;
      float lsum = Lpart[(size_t)(0 * 8 + p) * L_SEQ + q] +
                   Lpart[(size_t)(1 * 8 + p) * L_SEQ + q] +
                   Lpart[(size_t)(2 * 8 + p) * L_SEQ + q] +
                   Lpart[(size_t)(3 * 8 + p) * L_SEQ + q];
      float inv = 1.0f / lsum;
      float a8[8] = {0.f, 0.f, 0.f, 0.f, 0.f, 0.f, 0.f, 0.f};
#pragma unroll
      for (int ksp = 0; ksp < 4; ++ksp) {
        ushort8v v = *(const ushort8v*)(Opart + ((size_t)(ksp * 8 + p) * L_SEQ + q) * DH + c0);
#pragma unroll
        for (int j = 0; j < 8; ++j) a8[j] += bf2f(v[j]);
      }
      ushort8v o;
#pragma unroll
      for (int j = 0; j < 8; ++j) o[j] = f2bf(a8[j] * inv);
      *(ushort8v*)(As + row * CP + c0) = o;
    }
#pragma unroll
    for (int it = 0; it < 8; ++it) {
      int idx = t + it * 256;
      int row = idx >> 3, c0 = (idx & 7) * 8;
      const float* wp = fcw + (size_t)row * 256 + kb * 64 + c0;
      float4 wa = *(const float4*)(wp);
      float4 wb = *(const float4*)(wp + 4);
      uint4v pk = {cvtpk(wa.x, wa.y), cvtpk(wa.z, wa.w), cvtpk(wb.x, wb.y), cvtpk(wb.z, wb.w)};
      *(uint4v*)(Bs + row * CP + c0) = pk;
    }
    __syncthreads();
#pragma unroll
    for (int kc = 0; kc < 2; ++kc) {
      bf16x8 a = ld_frag(As + ln * CP + kc * 32 + g * 8);
      bf16x8 bb[4];
#pragma unroll
      for (int tn = 0; tn < 4; ++tn) bb[tn] = ld_frag(Bs + (wv * 64 + tn * 16 + ln) * CP + kc * 32 + g * 8);
#pragma unroll
      for (int tn = 0; tn < 4; ++tn)
        acc[tn] = __builtin_amdgcn_mfma_f32_16x16x32_bf16(a, bb[tn], acc[tn], 0, 0, 0);
    }
    __syncthreads();
  }
  float fb[4], lg[4], lb[4];
#pragma unroll
  for (int tn = 0; tn < 4; ++tn) {
    int o = wv * 64 + tn * 16 + ln;
    fb[tn] = fcb[o]; lg[tn] = lng[o]; lb[tn] = lnb[o];
  }
  {
    float ps[4] = {0.f, 0.f, 0.f, 0.f}, pq2[4] = {0.f, 0.f, 0.f, 0.f};
#pragma unroll
    for (int tn = 0; tn < 4; ++tn) {
      int o = wv * 64 + tn * 16 + ln;
#pragma unroll
      for (int r = 0; r < 4; ++r) {
        float v = acc[tn][r] + fb[tn] + resT[o * 17 + g * 4 + r];
        acc[tn][r] = v;
        ps[r] += v;
        pq2[r] += v * v;
      }
    }
#pragma unroll
    for (int r = 0; r < 4; ++r) {
      float s = ps[r], q2 = pq2[r];
#pragma unroll
      for (int off = 1; off < 16; off <<= 1) {
        s += __shfl_xor(s, off, 64);
        q2 += __shfl_xor(q2, off, 64);
      }
      if (ln == 0) {
        int row = g * 4 + r;
        redS[wv][row] = s;
        redQ[wv][row] = q2;
      }
    }
  }
  __syncthreads();
  if (t < 16) {
    float s = redS[0][t] + redS[1][t] + redS[2][t] + redS[3][t];
    float q2 = redQ[0][t] + redQ[1][t] + redQ[2][t] + redQ[3][t];
    float mu = s * (1.f / 256.f);
    float var = q2 * (1.f / 256.f) - mu * mu;
    muA[t] = mu;
    rsA[t] = rsqrtf(var + 1e-5f);
  }
  __syncthreads();
  // normalize into outB [l][c], then coalesced full-row stores
#pragma unroll
  for (int r = 0; r < 4; ++r) {
    int row = g * 4 + r;
    float mu = muA[row], rs = rsA[row];
#pragma unroll
    for (int tn = 0; tn < 4; ++tn) {
      int o = wv * 64 + tn * 16 + ln;
      outB[row * 260 + o] = (acc[tn][r] - mu) * rs * lg[tn] + lb[tn];
    }
  }
  __syncthreads();
#pragma unroll
  for (int it = 0; it < 4; ++it) {
    int idx = it * 256 + t;
    int row = idx >> 6;
    int c4 = (idx & 63) * 4;
    float4 v = *(const float4*)(outB + row * 260 + c4);
    *(float4*)(out + (size_t)(m0 + row) * 256 + c4) = v;
  }
}

extern "C" void kernel_launch(void* const* d_in, const int* in_sizes, int n_in,
                              void* d_out, int out_size, void* d_ws, size_t ws_size,
                              hipStream_t stream) {
  const float* q = (const float*)d_in[0];
  const float* w_qkv = (const float*)d_in[1];
  const float* fc_w = (const float*)d_in[2];
  const float* fc_b = (const float*)d_in[3];
  const float* ln_g = (const float*)d_in[4];
  const float* ln_b = (const float*)d_in[5];
  float* out = (float*)d_out;

  // workspace (shorts): Qh 4MB | QhT 4MB | Opart 16.7MB | Lpart 0.5MB  (~25.7MB)
  unsigned short* Qh = (unsigned short*)d_ws;    // [p][l][d]
  unsigned short* QhT = Qh + 2097152;            // [p][d][l]
  unsigned short* Opart = QhT + 2097152;         // [ks][p][q][d] bf16, 4*2M
  float* Lpart = (float*)(Opart + 8388608);      // [ks][p][q] fp32

  k_qkv<<<dim3(512), dim3(256), 0, stream>>>(q, w_qkv, Qh, QhT);
  k_attn<<<dim3(1024), dim3(256), 0, stream>>>(Qh, QhT, Opart, Lpart);
  k_fc<<<dim3(512), dim3(256), 0, stream>>>(Opart, Lpart, fc_w, q, fc_b, ln_g, ln_b, out);
}

// Round 8
// 131.250 us; speedup vs baseline: 1.0832x; 1.0436x over previous
//
#include <hip/hip_runtime.h>

#define L_SEQ 4096
#define DMODEL 256
#define DH 64
#define NKB 16   // key blocks (of 64) per workgroup: 4096 / 64 / ksplit(4)

typedef __attribute__((ext_vector_type(8))) __bf16 bf16x8;
typedef __attribute__((ext_vector_type(4))) float f32x4;
typedef __attribute__((ext_vector_type(16))) float f32x16;
typedef __attribute__((ext_vector_type(8))) unsigned short ushort8v;
typedef __attribute__((ext_vector_type(4))) unsigned short ushort4v;
typedef __attribute__((ext_vector_type(2))) unsigned int uint2v;
typedef __attribute__((ext_vector_type(4))) unsigned int uint4v;

__device__ __forceinline__ unsigned short f2bf(float f) {
  unsigned u = __builtin_bit_cast(unsigned, f);
  u += 0x7fffu + ((u >> 16) & 1u);
  return (unsigned short)(u >> 16);
}
__device__ __forceinline__ float bf2f(unsigned short h) {
  unsigned u = ((unsigned)h) << 16;
  return __builtin_bit_cast(float, u);
}
__device__ __forceinline__ bf16x8 ld_frag(const unsigned short* p) {
  return __builtin_bit_cast(bf16x8, *(const ushort8v*)p);
}
// pack 2 f32 -> 2 bf16 (RNE, same rounding as f2bf) in one VALU op
__device__ __forceinline__ unsigned cvtpk(float lo, float hi) {
  unsigned r;
  asm("v_cvt_pk_bf16_f32 %0, %1, %2" : "=v"(r) : "v"(lo), "v"(hi));
  return r;
}
// a.hi32lanes <-> b.lo32lanes (v_permlane32_swap_b32, gfx950)
__device__ __forceinline__ void plswap(unsigned& a, unsigned& b) {
  asm("v_permlane32_swap_b32 %0, %1" : "+v"(a), "+v"(b));
}
// raw v_exp_f32: D = 2^S0 (saves __expf's hidden *log2e mul; R5/R7-verified)
__device__ __forceinline__ float exp2raw(float x) {
  float r;
  asm("v_exp_f32 %0, %1" : "=v"(r) : "v"(x));
  return r;
}

// ---- 1. q [B,C,L] fp32 -> xbf [B*L, C] bf16; blocks >=512 convert weights ----
// (R3-exact: separate transpose measured faster than both fused variants R6/R7)
__global__ __launch_bounds__(256) void k_transpose(const float* __restrict__ q,
                                                   unsigned short* __restrict__ xbf,
                                                   const float* __restrict__ w,
                                                   const float* __restrict__ fcw,
                                                   unsigned short* __restrict__ wbf,
                                                   unsigned short* __restrict__ fcwbf) {
  int bx = blockIdx.x;
  int t = threadIdx.x;
  if (bx >= 512) {   // weight conversion tail
    int i = ((bx - 512) * 256 + t) * 4;
    float4 a = *(const float4*)(w + i);
    float4 b = *(const float4*)(fcw + i);
    ushort4v av = {f2bf(a.x), f2bf(a.y), f2bf(a.z), f2bf(a.w)};
    ushort4v bv = {f2bf(b.x), f2bf(b.y), f2bf(b.z), f2bf(b.w)};
    *(ushort4v*)(wbf + i) = av;
    *(ushort4v*)(fcwbf + i) = bv;
    return;
  }
  __shared__ float T[64 * 65];
  int b = bx >> 8, rest = bx & 255;
  int ct = rest >> 6, lt = rest & 63;
#pragma unroll
  for (int it = 0; it < 4; ++it) {
    int i = (t >> 4) + it * 16;
    int j0 = (t & 15) * 4;
    float4 v = *(const float4*)(q + ((size_t)(b * 256 + ct * 64 + i)) * 4096 + lt * 64 + j0);
    T[i * 65 + j0 + 0] = v.x;
    T[i * 65 + j0 + 1] = v.y;
    T[i * 65 + j0 + 2] = v.z;
    T[i * 65 + j0 + 3] = v.w;
  }
  __syncthreads();
#pragma unroll
  for (int it = 0; it < 2; ++it) {
    int l = (t >> 3) + it * 32;
    int c0 = (t & 7) * 8;
    ushort8v o;
#pragma unroll
    for (int k = 0; k < 8; ++k) o[k] = f2bf(T[(c0 + k) * 65 + l]);
    *(ushort8v*)(xbf + ((size_t)(b * 4096 + lt * 64 + l)) * 256 + ct * 64 + c0) = o;
  }
}

// ---- 2. QKV GEMM -> Qh [p][l][d] and QhT [p][d][l] (R3-exact) ----
#define KP2 136
__global__ __launch_bounds__(256) void k_qkv(const unsigned short* __restrict__ xbf,
                                             const unsigned short* __restrict__ wbf,
                                             unsigned short* __restrict__ Qh,
                                             unsigned short* __restrict__ QhT) {
  __shared__ unsigned short As[64 * KP2];
  __shared__ unsigned short Bs[64 * KP2];
  int bx = blockIdx.x;
  int mtile = bx >> 2, h = bx & 3;
  int m0 = mtile * 64;
  int b = m0 >> 12, l0 = m0 & 4095;
  int t = threadIdx.x;
  int wv = t >> 6, lane = t & 63, g = lane >> 4, ln = lane & 15;
  f32x4 acc[4] = {};
  for (int kb = 0; kb < 2; ++kb) {
#pragma unroll
    for (int it = 0; it < 4; ++it) {
      int idx = t + it * 256;
      int row = idx >> 4;
      int c0 = (idx & 15) * 8;
      *(ushort8v*)(As + row * KP2 + c0) =
          *(const ushort8v*)(xbf + (size_t)(m0 + row) * 256 + kb * 128 + c0);
      *(ushort8v*)(Bs + row * KP2 + c0) =
          *(const ushort8v*)(wbf + (size_t)(h * 64 + row) * 256 + kb * 128 + c0);
    }
    __syncthreads();
#pragma unroll
    for (int kc = 0; kc < 4; ++kc) {
      bf16x8 a = ld_frag(As + (wv * 16 + ln) * KP2 + kc * 32 + g * 8);
#pragma unroll
      for (int tn = 0; tn < 4; ++tn) {
        bf16x8 bb = ld_frag(Bs + (tn * 16 + ln) * KP2 + kc * 32 + g * 8);
        acc[tn] = __builtin_amdgcn_mfma_f32_16x16x32_bf16(a, bb, acc[tn], 0, 0, 0);
      }
    }
    __syncthreads();
  }
  size_t pbase = (size_t)(b * 4 + h);
  // ---- epilogue: bounce tiles through LDS, then dense 16-B stores ----
#pragma unroll
  for (int tn = 0; tn < 4; ++tn) {
#pragma unroll
    for (int r = 0; r < 4; ++r) {
      int lrow = wv * 16 + g * 4 + r;
      int d = tn * 16 + ln;
      unsigned short bv = f2bf(acc[tn][r]);
      As[lrow * 64 + (((d >> 3) ^ (lrow & 7)) * 8) + (d & 7)] = bv;
      Bs[d * 64 + (((lrow >> 3) ^ (d & 7)) * 8) + (lrow & 7)] = bv;
    }
  }
#pragma unroll
  for (int s = 0; s < 2; ++s) {
    int flat = s * 64 + lane;
    int lrow = wv * 16 + (flat >> 3);
    int c8 = lane & 7;
    ushort8v v = *(const ushort8v*)(As + lrow * 64 + ((c8 ^ (lrow & 7)) * 8));
    *(ushort8v*)(Qh + (pbase * L_SEQ + l0 + lrow) * DH + c8 * 8) = v;
  }
  __syncthreads();
#pragma unroll
  for (int s = 0; s < 2; ++s) {
    int flat = s * 256 + t;
    int drow = flat >> 3;
    int c8 = t & 7;
    ushort8v v = *(const ushort8v*)(Bs + drow * 64 + ((c8 ^ (drow & 7)) * 8));
    *(ushort8v*)(QhT + (pbase * DH + drow) * L_SEQ + l0 + c8 * 8) = v;
  }
}

// ---- 3. flash attention: R3/R5/R7-verified q-split body (measured best,
// 50.8-54us across runs) + exp2raw + s_setprio around MFMA clusters (T5:
// independent blocks per CU give the scheduler phase diversity to exploit).
// grid 1024 = 8p x 32qsup x 4ks.
__global__ __launch_bounds__(256, 2) void k_attn(const unsigned short* __restrict__ Qh,
                                                 const unsigned short* __restrict__ QhT,
                                                 unsigned short* __restrict__ Opart,
                                                 float* __restrict__ Lpart) {
  constexpr float C1 = 0.18033688011112042f;   // 0.125 * log2(e)
  constexpr float C2 = -23.083120654223414f;   // -16 * log2(e)
  __shared__ unsigned short smem[4 * 4096];  // K0 V0 K1 V1, 8KB each, 32 KB
  int bx = blockIdx.x;
  int p = bx & 7;
  int u = bx >> 3;
  int qsup = u & 31, ks = u >> 5;
  int t = threadIdx.x;
  int wv = t >> 6, lane = t & 63, ln = lane & 31, hi = lane >> 5;
  const unsigned short* Qp = Qh + (size_t)p * L_SEQ * DH;
  const unsigned short* QTp = QhT + (size_t)p * DH * L_SEQ;
  int q0 = qsup * 128;
  int qw = q0 + wv * 32;  // this wave's 32 q rows

  bf16x8 aQ[4];
#pragma unroll
  for (int kq = 0; kq < 4; ++kq)
    aQ[kq] = ld_frag(Qp + (size_t)(qw + ln) * DH + kq * 16 + hi * 8);

  f32x16 oacc[2] = {};   // [dt], O^T fragments
  float lacc = 0.f;      // per-lane partial l (half the keys)

  int srow0 = t >> 3, scol = t & 7;
  int srow1 = srow0 + 32;
  int sdst0 = srow0 * 64 + ((scol ^ (srow0 & 7)) * 8);
  int sdst1 = srow1 * 64 + ((scol ^ (srow1 & 7)) * 8);

  ushort8v kreg0, kreg1, vreg0, vreg1;
  {
    int kbase = (ks * NKB) * 64;
    kreg0 = *(const ushort8v*)(Qp + (size_t)(kbase + srow0) * DH + scol * 8);
    kreg1 = *(const ushort8v*)(Qp + (size_t)(kbase + srow1) * DH + scol * 8);
    vreg0 = *(const ushort8v*)(QTp + (size_t)srow0 * L_SEQ + kbase + scol * 8);
    vreg1 = *(const ushort8v*)(QTp + (size_t)srow1 * L_SEQ + kbase + scol * 8);
  }

  for (int kb = 0; kb < NKB; ++kb) {
    unsigned short* Kc = smem + (kb & 1) * 8192;
    unsigned short* Vc = Kc + 4096;
    // write buf[kb&1]: safe — its last readers (compute kb-2) are gated by
    // barrier(kb-1), which every wave passed before reaching this write.
    *(ushort8v*)(Kc + sdst0) = kreg0;
    *(ushort8v*)(Kc + sdst1) = kreg1;
    *(ushort8v*)(Vc + sdst0) = vreg0;
    *(ushort8v*)(Vc + sdst1) = vreg1;
    __syncthreads();
    if (kb + 1 < NKB) {  // issue next tile's loads; land during compute
      int kbase = (ks * NKB + kb + 1) * 64;
      kreg0 = *(const ushort8v*)(Qp + (size_t)(kbase + srow0) * DH + scol * 8);
      kreg1 = *(const ushort8v*)(Qp + (size_t)(kbase + srow1) * DH + scol * 8);
      vreg0 = *(const ushort8v*)(QTp + (size_t)srow0 * L_SEQ + kbase + scol * 8);
      vreg1 = *(const ushort8v*)(QTp + (size_t)srow1 * L_SEQ + kbase + scol * 8);
    }
#pragma unroll
    for (int mt = 0; mt < 2; ++mt) {
      int key = mt * 32 + ln;
      bf16x8 aK[4];
#pragma unroll
      for (int kq = 0; kq < 4; ++kq)
        aK[kq] = ld_frag(Kc + key * 64 + (((kq * 2 + hi) ^ (key & 7)) * 8));
      f32x16 s = {};
      __builtin_amdgcn_s_setprio(1);
#pragma unroll
      for (int kq = 0; kq < 4; ++kq)
        s = __builtin_amdgcn_mfma_f32_32x32x16_bf16(aK[kq], aQ[kq], s, 0, 0, 0);
      __builtin_amdgcn_s_setprio(0);
      // fixed-max softmax: p = 2^(s*C1 + C2) == exp(s/8 - 16)
      float pv[16];
#pragma unroll
      for (int r = 0; r < 16; ++r) pv[r] = exp2raw(fmaf(s[r], C1, C2));
      lacc += (((pv[0] + pv[1]) + (pv[2] + pv[3])) + ((pv[4] + pv[5]) + (pv[6] + pv[7]))) +
              (((pv[8] + pv[9]) + (pv[10] + pv[11])) + ((pv[12] + pv[13]) + (pv[14] + pv[15])));
      unsigned w0 = cvtpk(pv[0], pv[1]), w1 = cvtpk(pv[2], pv[3]);
      unsigned w2 = cvtpk(pv[4], pv[5]), w3 = cvtpk(pv[6], pv[7]);
      unsigned w4 = cvtpk(pv[8], pv[9]), w5 = cvtpk(pv[10], pv[11]);
      unsigned w6 = cvtpk(pv[12], pv[13]), w7 = cvtpk(pv[14], pv[15]);
      plswap(w0, w2);  // after: w0 = keys{lo:0,1 | hi:8,9}, w2 = {lo:4,5 | hi:12,13}
      plswap(w1, w3);  //        w1 = {lo:2,3 | hi:10,11}, w3 = {lo:6,7 | hi:14,15}
      plswap(w4, w6);  // same for keys 16..31 (chunk 1)
      plswap(w5, w7);
      uint4v c0 = {w0, w1, w2, w3};
      uint4v c1 = {w4, w5, w6, w7};
      bf16x8 pf0 = __builtin_bit_cast(bf16x8, c0);
      bf16x8 pf1 = __builtin_bit_cast(bf16x8, c1);
#pragma unroll
      for (int dt = 0; dt < 2; ++dt) {
        int d = dt * 32 + ln;
        bf16x8 vf0 = ld_frag(Vc + d * 64 + (((mt * 4 + 0 * 2 + hi) ^ (d & 7)) * 8));
        bf16x8 vf1 = ld_frag(Vc + d * 64 + (((mt * 4 + 1 * 2 + hi) ^ (d & 7)) * 8));
        __builtin_amdgcn_s_setprio(1);
        oacc[dt] = __builtin_amdgcn_mfma_f32_32x32x16_bf16(vf0, pf0, oacc[dt], 0, 0, 0);
        oacc[dt] = __builtin_amdgcn_mfma_f32_32x32x16_bf16(vf1, pf1, oacc[dt], 0, 0, 0);
        __builtin_amdgcn_s_setprio(0);
      }
    }
  }
  lacc += __shfl_xor(lacc, 32, 64);
  size_t pq = (size_t)(ks * 8 + p) * L_SEQ;
  if (lane < 32) Lpart[pq + qw + ln] = lacc;
  // O^T epilogue (verified): lane owns q = qw+ln;
  // reg r -> d = dt*32 + (r>>2)*8 + hi*4 + (r&3); cvt_pk pairs -> 8B stores.
#pragma unroll
  for (int dt = 0; dt < 2; ++dt) {
    size_t rb = (pq + qw + ln) * DH + dt * 32 + hi * 4;
#pragma unroll
    for (int g8 = 0; g8 < 4; ++g8) {
      uint2v wv2 = {cvtpk(oacc[dt][g8 * 4 + 0], oacc[dt][g8 * 4 + 1]),
                    cvtpk(oacc[dt][g8 * 4 + 2], oacc[dt][g8 * 4 + 3])};
      *(uint2v*)(Opart + rb + g8 * 8) = wv2;
    }
  }
}

// ---- 4. FC GEMM (fused ks-merge) + bias + residual + LayerNorm (R3-exact,
// the version in the 133.4us best-total measurement) ----
#define CP 72
__global__ __launch_bounds__(256) void k_fc(const unsigned short* __restrict__ Opart,
                                            const float* __restrict__ Lpart,
                                            const unsigned short* __restrict__ fcwbf,
                                            const float* __restrict__ qres,
                                            const float* __restrict__ fcb,
                                            const float* __restrict__ lng,
                                            const float* __restrict__ lnb,
                                            float* __restrict__ out) {
  __shared__ unsigned short As[32 * CP];
  __shared__ unsigned short Bs[256 * CP];
  __shared__ float redS[4][32], redQ[4][32], muA[32], rsA[32];
  int bx = blockIdx.x;
  int m0 = bx * 32;
  int b = m0 >> 12, lpart = m0 & 4095;
  int t = threadIdx.x;
  int wv = t >> 6, lane = t & 63, g = lane >> 4, ln = lane & 15;
  f32x4 acc[2][4] = {};
  for (int kb = 0; kb < 4; ++kb) {   // kb == head index for A-staging
    {
      int row = t >> 3, c0 = (t & 7) * 8;
      int q = lpart + row;
      int p = b * 4 + kb;
      float lsum = Lpart[(size_t)(0 * 8 + p) * L_SEQ + q] +
                   Lpart[(size_t)(1 * 8 + p) * L_SEQ + q] +
                   Lpart[(size_t)(2 * 8 + p) * L_SEQ + q] +
                   Lpart[(size_t)(3 * 8 + p) * L_SEQ + q];
      float inv = 1.0f / lsum;
      float a8[8] = {0.f, 0.f, 0.f, 0.f, 0.f, 0.f, 0.f, 0.f};
#pragma unroll
      for (int ksp = 0; ksp < 4; ++ksp) {
        ushort8v v = *(const ushort8v*)(Opart + ((size_t)(ksp * 8 + p) * L_SEQ + q) * DH + c0);
#pragma unroll
        for (int j = 0; j < 8; ++j) a8[j] += bf2f(v[j]);
      }
      ushort8v o;
#pragma unroll
      for (int j = 0; j < 8; ++j) o[j] = f2bf(a8[j] * inv);
      *(ushort8v*)(As + row * CP + c0) = o;
    }
#pragma unroll
    for (int it = 0; it < 8; ++it) {
      int idx = t + it * 256;
      int row = idx >> 3, c0 = (idx & 7) * 8;
      *(ushort8v*)(Bs + row * CP + c0) =
          *(const ushort8v*)(fcwbf + (size_t)row * 256 + kb * 64 + c0);
    }
    __syncthreads();
#pragma unroll
    for (int kc = 0; kc < 2; ++kc) {
      bf16x8 a[2], bb[4];
#pragma unroll
      for (int mt = 0; mt < 2; ++mt) a[mt] = ld_frag(As + (mt * 16 + ln) * CP + kc * 32 + g * 8);
#pragma unroll
      for (int tn = 0; tn < 4; ++tn) bb[tn] = ld_frag(Bs + (wv * 64 + tn * 16 + ln) * CP + kc * 32 + g * 8);
#pragma unroll
      for (int mt = 0; mt < 2; ++mt)
#pragma unroll
        for (int tn = 0; tn < 4; ++tn)
          acc[mt][tn] = __builtin_amdgcn_mfma_f32_16x16x32_bf16(a[mt], bb[tn], acc[mt][tn], 0, 0, 0);
    }
    __syncthreads();
  }
  float fb[4], lg[4], lb[4];
#pragma unroll
  for (int tn = 0; tn < 4; ++tn) {
    int o = wv * 64 + tn * 16 + ln;
    fb[tn] = fcb[o]; lg[tn] = lng[o]; lb[tn] = lnb[o];
  }
#pragma unroll
  for (int mt = 0; mt < 2; ++mt) {
    float ps[4] = {0.f, 0.f, 0.f, 0.f}, pq2[4] = {0.f, 0.f, 0.f, 0.f};
#pragma unroll
    for (int tn = 0; tn < 4; ++tn) {
      int o = wv * 64 + tn * 16 + ln;
      float4 res = *(const float4*)(qres + ((size_t)(b * 256 + o)) * 4096 + lpart + mt * 16 + g * 4);
      float rv[4] = {res.x, res.y, res.z, res.w};
#pragma unroll
      for (int r = 0; r < 4; ++r) {
        float v = acc[mt][tn][r] + fb[tn] + rv[r];
        acc[mt][tn][r] = v;
        ps[r] += v;
        pq2[r] += v * v;
      }
    }
#pragma unroll
    for (int r = 0; r < 4; ++r) {
      float s = ps[r], q2 = pq2[r];
#pragma unroll
      for (int off = 1; off < 16; off <<= 1) {
        s += __shfl_xor(s, off, 64);
        q2 += __shfl_xor(q2, off, 64);
      }
      if (ln == 0) {
        int row = mt * 16 + g * 4 + r;
        redS[wv][row] = s;
        redQ[wv][row] = q2;
      }
    }
  }
  __syncthreads();
  if (t < 32) {
    float s = redS[0][t] + redS[1][t] + redS[2][t] + redS[3][t];
    float q2 = redQ[0][t] + redQ[1][t] + redQ[2][t] + redQ[3][t];
    float mu = s * (1.f / 256.f);
    float var = q2 * (1.f / 256.f) - mu * mu;
    muA[t] = mu;
    rsA[t] = rsqrtf(var + 1e-5f);
  }
  __syncthreads();
#pragma unroll
  for (int mt = 0; mt < 2; ++mt) {
#pragma unroll
    for (int r = 0; r < 4; ++r) {
      int row = mt * 16 + g * 4 + r;
      float mu = muA[row], rs = rsA[row];
#pragma unroll
      for (int tn = 0; tn < 4; ++tn) {
        int o = wv * 64 + tn * 16 + ln;
        out[(size_t)(m0 + row) * 256 + o] = (acc[mt][tn][r] - mu) * rs * lg[tn] + lb[tn];
      }
    }
  }
}

extern "C" void kernel_launch(void* const* d_in, const int* in_sizes, int n_in,
                              void* d_out, int out_size, void* d_ws, size_t ws_size,
                              hipStream_t stream) {
  const float* q = (const float*)d_in[0];
  const float* w_qkv = (const float*)d_in[1];
  const float* fc_w = (const float*)d_in[2];
  const float* fc_b = (const float*)d_in[3];
  const float* ln_g = (const float*)d_in[4];
  const float* ln_b = (const float*)d_in[5];
  float* out = (float*)d_out;

  unsigned short* wbf = (unsigned short*)d_ws;   // 65536
  unsigned short* fcwbf = wbf + 65536;           // 65536
  unsigned short* xbf = fcwbf + 65536;           // 8192*256
  unsigned short* Qh = xbf + 2097152;            // [p][l][d]
  unsigned short* QhT = Qh + 2097152;            // [p][d][l]
  unsigned short* Opart = QhT + 2097152;         // [ks][p][q][d] bf16, 4*2M
  float* Lpart = (float*)(Opart + 8388608);      // [ks][p][q] fp32
  // total ws use: ~30.1 MB

  k_transpose<<<dim3(576), dim3(256), 0, stream>>>(q, xbf, w_qkv, fc_w, wbf, fcwbf);
  k_qkv<<<dim3(512), dim3(256), 0, stream>>>(xbf, wbf, Qh, QhT);
  k_attn<<<dim3(1024), dim3(256), 0, stream>>>(Qh, QhT, Opart, Lpart);
  k_fc<<<dim3(256), dim3(256), 0, stream>>>(Opart, Lpart, fcwbf, q, fc_b, ln_g, ln_b, out);
}